// Round 4
// baseline (690.774 us; speedup 1.0000x reference)
//
#include <hip/hip_runtime.h>
#include <hip/hip_bf16.h>

// Problem constants (match reference)
constexpr int B = 8192;
constexpr int G = 1024;
constexpr int E = 256;
constexpr int K = 2048;
constexpr float P_NULL = 0.1f;
constexpr int N_STEP = 4;

typedef unsigned short u16;
typedef short bf16x8 __attribute__((ext_vector_type(8)));
typedef float f32x4 __attribute__((ext_vector_type(4)));

// ---------------------------------------------------------------------------
// bf16 <-> f32 (RNE)
// ---------------------------------------------------------------------------
__device__ inline u16 f2bf(float f) {
    union { float f; uint32_t u; } cv;
    cv.f = f;
    const uint32_t u = cv.u;
    return (u16)((u + 0x7fffu + ((u >> 16) & 1u)) >> 16);
}
__device__ inline float bf2f(u16 h) {
    union { uint32_t u; float f; } cv;
    cv.u = ((uint32_t)h) << 16;
    return cv.f;
}
__device__ inline void unpack8(uint4 u, float* v) {
    v[0] = bf2f((u16)(u.x & 0xffff)); v[1] = bf2f((u16)(u.x >> 16));
    v[2] = bf2f((u16)(u.y & 0xffff)); v[3] = bf2f((u16)(u.y >> 16));
    v[4] = bf2f((u16)(u.z & 0xffff)); v[5] = bf2f((u16)(u.z >> 16));
    v[6] = bf2f((u16)(u.w & 0xffff)); v[7] = bf2f((u16)(u.w >> 16));
}
__device__ inline uint4 pack8(const float* v) {
    uint4 u;
    u.x = (uint32_t)f2bf(v[0]) | ((uint32_t)f2bf(v[1]) << 16);
    u.y = (uint32_t)f2bf(v[2]) | ((uint32_t)f2bf(v[3]) << 16);
    u.z = (uint32_t)f2bf(v[4]) | ((uint32_t)f2bf(v[5]) << 16);
    u.w = (uint32_t)f2bf(v[6]) | ((uint32_t)f2bf(v[7]) << 16);
    return u;
}

// async global->LDS, 16B per lane
typedef __attribute__((address_space(1))) const void* gaddr_t;
typedef __attribute__((address_space(3))) void* laddr_t;
__device__ inline void gload_lds16(const void* g, void* l) {
    __builtin_amdgcn_global_load_lds((gaddr_t)g, (laddr_t)l, 16, 0, 0);
}

// XCD-aware tile swizzle: linear id % 8 = XCD (round-robin dispatch).
// Give each XCD a contiguous band of row-tiles covering ALL col-tiles, so the
// A band + B matrix stay resident in that XCD's 4MB L2.
// Requires gridDim.y % 8 == 0.
__device__ inline void swizzle_tiles(int& tr, int& tc) {
    const int cx = gridDim.x, cy = gridDim.y;
    const int id = blockIdx.y * cx + blockIdx.x;
    const int k = id & 7;
    const int q = id >> 3;
    tr = k * (cy >> 3) + q / cx;
    tc = q % cx;
}

// ---------------------------------------------------------------------------
// Reduction helpers (256-thread blocks, wave64)
// ---------------------------------------------------------------------------
__device__ inline float wave_sum(float v) {
#pragma unroll
    for (int off = 32; off > 0; off >>= 1) v += __shfl_down(v, off, 64);
    return v;
}
__device__ inline float wave_max(float v) {
#pragma unroll
    for (int off = 32; off > 0; off >>= 1) v = fmaxf(v, __shfl_down(v, off, 64));
    return v;
}
__device__ inline float block_sum256(float v, float* sm) {
    v = wave_sum(v);
    const int w = threadIdx.x >> 6;
    if ((threadIdx.x & 63) == 0) sm[w] = v;
    __syncthreads();
    const float r = sm[0] + sm[1] + sm[2] + sm[3];
    __syncthreads();
    return r;
}
__device__ inline float block_max256(float v, float* sm) {
    v = wave_max(v);
    const int w = threadIdx.x >> 6;
    if ((threadIdx.x & 63) == 0) sm[w] = v;
    __syncthreads();
    const float r = fmaxf(fmaxf(sm[0], sm[1]), fmaxf(sm[2], sm[3]));
    __syncthreads();
    return r;
}

// ---------------------------------------------------------------------------
// f32 -> bf16 flat convert, 8 elems/thread
// ---------------------------------------------------------------------------
__global__ __launch_bounds__(256) void f2bf_kernel(
    const float* __restrict__ in, u16* __restrict__ out, int n) {
    const int i = (blockIdx.x * 256 + threadIdx.x) * 8;
    if (i + 7 >= n) {
        for (int j = i; j < n; ++j) out[j] = f2bf(in[j]);
        return;
    }
    const float4 a = *(const float4*)(in + i);
    const float4 b = *(const float4*)(in + i + 4);
    float v[8] = {a.x, a.y, a.z, a.w, b.x, b.y, b.z, b.w};
    *(uint4*)(out + i) = pack8(v);
}

// ---------------------------------------------------------------------------
// f32 (R,C) -> bf16 (C,R) transpose. grid (C/32, R/32), block 256.
// ---------------------------------------------------------------------------
__global__ __launch_bounds__(256) void transpose_bf_kernel(
    const float* __restrict__ in, u16* __restrict__ out, int R, int C) {
    __shared__ float tile[32][33];
    const int bx = blockIdx.x * 32, by = blockIdx.y * 32;
    const int x = threadIdx.x & 31, y0 = threadIdx.x >> 5;
#pragma unroll
    for (int yy = 0; yy < 32; yy += 8)
        tile[y0 + yy][x] = in[(size_t)(by + y0 + yy) * C + bx + x];
    __syncthreads();
#pragma unroll
    for (int yy = 0; yy < 32; yy += 8)
        out[(size_t)(bx + y0 + yy) * R + by + x] = f2bf(tile[x][y0 + yy]);
}

// ---------------------------------------------------------------------------
// Column mean-of-squares (f32 in): out[k] += inv_rows * sum_r M[r,k]^2
// ---------------------------------------------------------------------------
__global__ __launch_bounds__(256) void colsq_kernel(
    const float* __restrict__ M, int rows, int cols, float inv_rows,
    float* __restrict__ out) {
    const int k = blockIdx.x * 256 + threadIdx.x;
    const int r0 = blockIdx.y * 128;
    const int r1 = min(r0 + 128, rows);
    float s = 0.f;
    for (int r = r0; r < r1; ++r) {
        const float v = M[(size_t)r * cols + k];
        s = fmaf(v, v, s);
    }
    atomicAdd(out + k, s * inv_rows);
}

// ---------------------------------------------------------------------------
// MFMA bf16 GEMM (128x128 tile): C = A(M,Kd) x Bm(N,Kd)^T
// 256 threads = 4 waves, each wave 64x64 via 4x4 16x16x32 MFMAs.
// Epilogues: EPI_BIAS_BF16 (bf16 = alpha*acc - bias[col], LDS-repacked
// vectorized store), EPI_BF16, EPI_LOSS (row MSE vs X, atomic).
// ---------------------------------------------------------------------------
enum { EPI_BIAS_BF16 = 0, EPI_BF16 = 1, EPI_LOSS = 2 };
constexpr int STG = 136;  // stage stride (u16): breaks bank conflicts, keeps 16B align

template <int EPI>
__global__ __launch_bounds__(256) void mfma_gemm_kernel(
    const u16* __restrict__ A, const u16* __restrict__ Bm,
    void* __restrict__ Cout, const float* __restrict__ bias,
    const float* __restrict__ X, int M, int N, int Kd, float alpha) {
    __shared__ u16 smem[17408];  // As 8192 | Bs 8192 ; reused as 128xSTG stage
    u16* As = smem;
    u16* Bs = smem + 8192;
    const int tid = threadIdx.x;
    int btr, btc;
    swizzle_tiles(btr, btc);
    const int row0 = btr * 128, col0 = btc * 128;
    const int lane = tid & 63, wave = tid >> 6;
    const int wr = (wave >> 1) * 64, wc = (wave & 1) * 64;
    const int tx = lane & 15, quad = lane >> 4;

    f32x4 acc[4][4] = {};

    for (int k0 = 0; k0 < Kd; k0 += 64) {
#pragma unroll
        for (int l = 0; l < 4; ++l) {
            const int lin = l * 2048 + tid * 8;
            const int r = lin >> 6, c = lin & 63;
            gload_lds16(A + (size_t)(row0 + r) * Kd + k0 + c, &As[lin]);
        }
#pragma unroll
        for (int l = 0; l < 4; ++l) {
            const int lin = l * 2048 + tid * 8;
            const int r = lin >> 6, c = lin & 63;
            gload_lds16(Bm + (size_t)(col0 + r) * Kd + k0 + c, &Bs[lin]);
        }
        __syncthreads();
#pragma unroll
        for (int ks = 0; ks < 2; ++ks) {
            bf16x8 af[4], bfr[4];
#pragma unroll
            for (int i = 0; i < 4; ++i)
                af[i] = *(const bf16x8*)&As[(wr + i * 16 + tx) * 64 + ks * 32 + quad * 8];
#pragma unroll
            for (int j = 0; j < 4; ++j)
                bfr[j] = *(const bf16x8*)&Bs[(wc + j * 16 + tx) * 64 + ks * 32 + quad * 8];
#pragma unroll
            for (int i = 0; i < 4; ++i)
#pragma unroll
                for (int j = 0; j < 4; ++j)
                    acc[i][j] = __builtin_amdgcn_mfma_f32_16x16x32_bf16(
                        af[i], bfr[j], acc[i][j], 0, 0, 0);
        }
        __syncthreads();
    }

    // C/D layout (m89): col = lane&15, row = (lane>>4)*4 + reg
    if (EPI == EPI_LOSS) {
        float* loss = (float*)Cout;
        const float inv_n = 1.0f / (float)N;
#pragma unroll
        for (int i = 0; i < 4; ++i) {
#pragma unroll
            for (int r = 0; r < 4; ++r) {
                const int row = row0 + wr + i * 16 + quad * 4 + r;
                float s = 0.f;
#pragma unroll
                for (int j = 0; j < 4; ++j) {
                    const int col = col0 + wc + j * 16 + tx;
                    const float d = acc[i][j][r] - X[(size_t)row * N + col];
                    s = fmaf(d, d, s);
                }
                s += __shfl_xor(s, 1, 64);
                s += __shfl_xor(s, 2, 64);
                s += __shfl_xor(s, 4, 64);
                s += __shfl_xor(s, 8, 64);
                if (tx == 0) atomicAdd(&loss[row], s * inv_n);
            }
        }
    } else {
        // repack through LDS, then coalesced uint4 stores
        u16* C = (u16*)Cout;
#pragma unroll
        for (int i = 0; i < 4; ++i)
#pragma unroll
            for (int j = 0; j < 4; ++j) {
                const int col = wc + j * 16 + tx;
                float b = (EPI == EPI_BIAS_BF16) ? bias[col0 + col] : 0.f;
#pragma unroll
                for (int r = 0; r < 4; ++r) {
                    const int row = wr + i * 16 + quad * 4 + r;
                    float v = acc[i][j][r];
                    if (EPI == EPI_BIAS_BF16) v = fmaf(v, alpha, -b);
                    smem[row * STG + col] = f2bf(v);
                }
            }
        __syncthreads();
        const int rr = tid >> 1, half = (tid & 1) * 64;
#pragma unroll
        for (int u = 0; u < 8; ++u) {
            *(uint4*)(C + (size_t)(row0 + rr) * N + col0 + half + u * 8) =
                *(const uint4*)&smem[rr * STG + half + u * 8];
        }
    }
}

// ---------------------------------------------------------------------------
// MFMA bf16 GEMM variant (64x128 tile) for the (B,E)-output GEMMs:
// doubles the grid (256 blocks) so all CUs are busy. EPI_BF16 only.
// ---------------------------------------------------------------------------
__global__ __launch_bounds__(256) void mfma_gemm64_kernel(
    const u16* __restrict__ A, const u16* __restrict__ Bm,
    u16* __restrict__ C, int M, int N, int Kd) {
    __shared__ u16 smem[12288];  // As 4096 | Bs 8192 ; stage 64xSTG = 8704
    u16* As = smem;
    u16* Bs = smem + 4096;
    const int tid = threadIdx.x;
    int btr, btc;
    swizzle_tiles(btr, btc);
    const int row0 = btr * 64, col0 = btc * 128;
    const int lane = tid & 63, wave = tid >> 6;
    const int wr = (wave >> 1) * 32, wc = (wave & 1) * 64;
    const int tx = lane & 15, quad = lane >> 4;

    f32x4 acc[2][4] = {};

    for (int k0 = 0; k0 < Kd; k0 += 64) {
#pragma unroll
        for (int l = 0; l < 2; ++l) {
            const int lin = l * 2048 + tid * 8;
            const int r = lin >> 6, c = lin & 63;
            gload_lds16(A + (size_t)(row0 + r) * Kd + k0 + c, &As[lin]);
        }
#pragma unroll
        for (int l = 0; l < 4; ++l) {
            const int lin = l * 2048 + tid * 8;
            const int r = lin >> 6, c = lin & 63;
            gload_lds16(Bm + (size_t)(col0 + r) * Kd + k0 + c, &Bs[lin]);
        }
        __syncthreads();
#pragma unroll
        for (int ks = 0; ks < 2; ++ks) {
            bf16x8 af[2], bfr[4];
#pragma unroll
            for (int i = 0; i < 2; ++i)
                af[i] = *(const bf16x8*)&As[(wr + i * 16 + tx) * 64 + ks * 32 + quad * 8];
#pragma unroll
            for (int j = 0; j < 4; ++j)
                bfr[j] = *(const bf16x8*)&Bs[(wc + j * 16 + tx) * 64 + ks * 32 + quad * 8];
#pragma unroll
            for (int i = 0; i < 2; ++i)
#pragma unroll
                for (int j = 0; j < 4; ++j)
                    acc[i][j] = __builtin_amdgcn_mfma_f32_16x16x32_bf16(
                        af[i], bfr[j], acc[i][j], 0, 0, 0);
        }
        __syncthreads();
    }

#pragma unroll
    for (int i = 0; i < 2; ++i)
#pragma unroll
        for (int j = 0; j < 4; ++j)
#pragma unroll
            for (int r = 0; r < 4; ++r) {
                const int row = wr + i * 16 + quad * 4 + r;
                const int col = wc + j * 16 + tx;
                smem[row * STG + col] = f2bf(acc[i][j][r]);
            }
    __syncthreads();
    const int rr = tid >> 2, qo = (tid & 3) * 32;
#pragma unroll
    for (int u = 0; u < 4; ++u) {
        *(uint4*)(C + (size_t)(row0 + rr) * N + col0 + qo + u * 8) =
            *(const uint4*)&smem[rr * STG + qo + u * 8];
    }
}

// ---------------------------------------------------------------------------
// Row softmax over K=2048 (bf16 in/out). One block (256 thr) per row.
// ---------------------------------------------------------------------------
__global__ __launch_bounds__(256) void softmax_bf_kernel(
    const u16* __restrict__ T, u16* __restrict__ P) {
    __shared__ float sm[4];
    const size_t base = (size_t)blockIdx.x * K + (size_t)threadIdx.x * 8;
    float v[8];
    unpack8(*(const uint4*)(T + base), v);
    float m = v[0];
#pragma unroll
    for (int i = 1; i < 8; ++i) m = fmaxf(m, v[i]);
    m = block_max256(m, sm);
    float s = 0.f;
#pragma unroll
    for (int i = 0; i < 8; ++i) {
        v[i] = __expf(v[i] - m);
        s += v[i];
    }
    s = block_sum256(s, sm);
    const float inv = 1.f / s;
#pragma unroll
    for (int i = 0; i < 8; ++i) v[i] *= inv;
    *(uint4*)(P + base) = pack8(v);
}

// ---------------------------------------------------------------------------
// Loop reweight: XP = pik*exp(t - rowmax); XP /= rowsum  (bf16 in/out)
// ---------------------------------------------------------------------------
__global__ __launch_bounds__(256) void reweight_bf_kernel(
    const u16* __restrict__ T, const u16* __restrict__ P,
    u16* __restrict__ XP) {
    __shared__ float sm[4];
    const size_t base = (size_t)blockIdx.x * K + (size_t)threadIdx.x * 8;
    float v[8], p[8];
    unpack8(*(const uint4*)(T + base), v);
    unpack8(*(const uint4*)(P + base), p);
    float m = v[0];
#pragma unroll
    for (int i = 1; i < 8; ++i) m = fmaxf(m, v[i]);
    m = block_max256(m, sm);
    float s = 0.f;
#pragma unroll
    for (int i = 0; i < 8; ++i) {
        v[i] = p[i] * __expf(v[i] - m);
        s += v[i];
    }
    s = block_sum256(s, sm);
    const float inv = 1.f / s;
#pragma unroll
    for (int i = 0; i < 8; ++i) v[i] *= inv;
    *(uint4*)(XP + base) = pack8(v);
}

// ---------------------------------------------------------------------------
// Row mean of squares of Z (B,E) bf16: x2[row] = mean(Z[row,:]^2)
// ---------------------------------------------------------------------------
__global__ __launch_bounds__(256) void rowmeansq_bf_kernel(
    const u16* __restrict__ Z, float* __restrict__ out) {
    __shared__ float sm[4];
    const float v = bf2f(Z[(size_t)blockIdx.x * E + threadIdx.x]);
    const float s = block_sum256(v * v, sm);
    if (threadIdx.x == 0) out[blockIdx.x] = s * (1.0f / (float)E);
}

// ---------------------------------------------------------------------------
// Decode: xq = exp(t - x2[row]); XQ = xq / (P_NULL + rowsum(xq))  (bf16)
// ---------------------------------------------------------------------------
__global__ __launch_bounds__(256) void decode_bf_kernel(
    const u16* __restrict__ T, const float* __restrict__ x2z,
    u16* __restrict__ XQ) {
    __shared__ float sm[4];
    const size_t base = (size_t)blockIdx.x * K + (size_t)threadIdx.x * 8;
    const float x2 = x2z[blockIdx.x];
    float v[8];
    unpack8(*(const uint4*)(T + base), v);
    float s = 0.f;
#pragma unroll
    for (int i = 0; i < 8; ++i) {
        v[i] = __expf(v[i] - x2);
        s += v[i];
    }
    s = block_sum256(s, sm);
    const float scale = 1.f / (P_NULL + s);
#pragma unroll
    for (int i = 0; i < 8; ++i) v[i] *= scale;
    *(uint4*)(XQ + base) = pack8(v);
}

// ---------------------------------------------------------------------------
extern "C" void kernel_launch(void* const* d_in, const int* in_sizes, int n_in,
                              void* d_out, int out_size, void* d_ws, size_t ws_size,
                              hipStream_t stream) {
    const float* images = (const float*)d_in[0];  // (B,G)
    const float* xa     = (const float*)d_in[1];  // (G,K)
    const float* xb     = (const float*)d_in[2];  // (E,K)
    float* out = (float*)d_out;                   // (B,)

    // workspace carve-up (u16 elements, all regions 16B-aligned)
    u16* img_bf = (u16*)d_ws;                      // B*G
    u16* xa_bf  = img_bf + (size_t)B * G;          // G*K
    u16* xaT_bf = xa_bf + (size_t)G * K;           // K*G
    u16* xb_bf  = xaT_bf + (size_t)K * G;          // E*K
    u16* xbT_bf = xb_bf + (size_t)E * K;           // K*E
    u16* pik_bf = xbT_bf + (size_t)K * E;          // B*K
    u16* t_bf   = pik_bf + (size_t)B * K;          // B*K
    u16* xp_bf  = t_bf + (size_t)B * K;            // B*K
    u16* z_bf   = xp_bf + (size_t)B * K;           // B*E
    float* x2z  = (float*)(z_bf + (size_t)B * E);  // B
    float* c2a  = x2z + B;                         // K
    float* c2b  = c2a + K;                         // K

    (void)hipMemsetAsync(d_out, 0, (size_t)B * sizeof(float), stream);
    (void)hipMemsetAsync(c2a, 0, (size_t)2 * K * sizeof(float), stream);

    // bf16 conversions + transposes
    f2bf_kernel<<<(B * G) / 2048, 256, 0, stream>>>(images, img_bf, B * G);
    f2bf_kernel<<<(G * K) / 2048, 256, 0, stream>>>(xa, xa_bf, G * K);
    f2bf_kernel<<<(E * K) / 2048, 256, 0, stream>>>(xb, xb_bf, E * K);
    transpose_bf_kernel<<<dim3(K / 32, G / 32), 256, 0, stream>>>(xa, xaT_bf, G, K);
    transpose_bf_kernel<<<dim3(K / 32, E / 32), 256, 0, stream>>>(xb, xbT_bf, E, K);

    // c2a[k] = mean_g xa[g,k]^2 ; c2b[k] = mean_e xb[e,k]^2
    colsq_kernel<<<dim3(K / 256, G / 128), 256, 0, stream>>>(xa, G, K, 1.0f / G, c2a);
    colsq_kernel<<<dim3(K / 256, E / 128), 256, 0, stream>>>(xb, E, K, 1.0f / E, c2b);

    // encode: t = images@xa * (2/G) - c2a
    mfma_gemm_kernel<EPI_BIAS_BF16><<<dim3(K / 128, B / 128), 256, 0, stream>>>(
        img_bf, xaT_bf, t_bf, c2a, nullptr, B, K, G, 2.0f / (float)G);
    softmax_bf_kernel<<<B, 256, 0, stream>>>(t_bf, pik_bf);

    // z = pik @ xb^T   (64-row tile variant: 256 blocks, full GPU)
    mfma_gemm64_kernel<<<dim3(E / 128, B / 64), 256, 0, stream>>>(
        pik_bf, xb_bf, z_bf, B, E, K);

    for (int s = 0; s < N_STEP; ++s) {
        // t = z@xb * (2/E) - c2b
        mfma_gemm_kernel<EPI_BIAS_BF16><<<dim3(K / 128, B / 128), 256, 0, stream>>>(
            z_bf, xbT_bf, t_bf, c2b, nullptr, B, K, E, 2.0f / (float)E);
        // xp = pik*exp(t - max) / sum
        reweight_bf_kernel<<<B, 256, 0, stream>>>(t_bf, pik_bf, xp_bf);
        // z = xp @ xb^T
        mfma_gemm64_kernel<<<dim3(E / 128, B / 64), 256, 0, stream>>>(
            xp_bf, xb_bf, z_bf, B, E, K);
    }

    // decode
    rowmeansq_bf_kernel<<<B, 256, 0, stream>>>(z_bf, x2z);
    mfma_gemm_kernel<EPI_BIAS_BF16><<<dim3(K / 128, B / 128), 256, 0, stream>>>(
        z_bf, xbT_bf, t_bf, c2b, nullptr, B, K, E, 2.0f / (float)E);
    decode_bf_kernel<<<B, 256, 0, stream>>>(t_bf, x2z, xp_bf);

    // recon = xq @ xa^T ; loss[b] = mean_g (recon - images)^2
    mfma_gemm_kernel<EPI_LOSS><<<dim3(G / 128, B / 128), 256, 0, stream>>>(
        xp_bf, xa_bf, out, nullptr, images, B, G, K, 1.0f);
}